// Round 1
// 97.054 us; speedup vs baseline: 1.0528x; 1.0528x over previous
//
#include <hip/hip_runtime.h>
#include <hip/hip_bf16.h>

// Conv2.5D disparity-masked conv as implicit GEMM on bf16 MFMA, v7.
// v7 vs v6: 2-row x 64-px blocks (512 thr / 8 waves, grid 1024, 4 blk/CU,
// still 32 waves/CU) cut x halo staging from 3.09x to 2.06x compulsory;
// bijective XCD swizzle gives each XCD a contiguous 64-row strip so halo
// re-reads hit the local L2; build_wA spread over 54 CUs. Per-wave compute,
// masks, exact-skip, fragment layouts and epilogue identical to proven v6.

#define IN_C 32
#define OUT_C 64
#define IMG 256
#define HW 66           // halo width: 64 + 2

typedef __bf16 bf16x8 __attribute__((ext_vector_type(8)));
typedef float f32x16 __attribute__((ext_vector_type(16)));
union B128 { uint4 i4; bf16x8 v; };

// ---- prep: weights into A-fragment order (proven rounds 2-5) ---------------
// wA[q][ot][lane] (uint4 each), q = p*6 + t*2 + chalf.
// A[m = ot*32 + (lane&31)][k_in = (lane>>5)*8 + j], c = chalf*16 + k_in.
__global__ void build_wA(const float* __restrict__ w0,
                         const float* __restrict__ w1,
                         const float* __restrict__ w2,
                         __hip_bfloat16* __restrict__ wA) {
    int tid = blockIdx.x * 128 + threadIdx.x;      // q*128 + ot*64 + lane
    if (tid >= 54 * 128) return;
    int lane  = tid & 63;
    int ot    = (tid >> 6) & 1;
    int q     = tid >> 7;
    int p     = q / 6;
    int rm    = q - p * 6;
    int t     = rm >> 1;
    int chalf = rm & 1;
    int o     = ot * 32 + (lane & 31);
    int cbase = chalf * 16 + (lane >> 5) * 8;
    const float* w = (t == 0) ? w0 : (t == 1) ? w1 : w2;
    __hip_bfloat16* dst = wA + (size_t)tid * 8;
    #pragma unroll
    for (int j = 0; j < 8; ++j) {
        float v = w[(o * IN_C + cbase + j) * 9 + p];
        dst[j] = __float2bfloat16(v);
    }
}

// ---- main kernel -----------------------------------------------------------
// Block = 2 rows x 64 px of one image. Grid 1024 (4/CU), 512 thr = 8 waves.
// Wave w: ot = w&1 (32 outs), ph = (w>>1)&1 (32 px), rloc = w>>2 (row 0/1).
__global__ __launch_bounds__(512, 8) void conv25d_mfma7(
    const float* __restrict__ x, const float* __restrict__ disp,
    const float* __restrict__ fx, const float* __restrict__ baseline,
    const uint4* __restrict__ wA, float* __restrict__ out) {

    // x halo strip as 4 k-slot planes x 4 halo rows: sx[(s*4 + rr)*HW + cc2].
    // plane s holds channels [s*8, s*8+8) of pixel (row0+rr-1, colbase+cc2-1).
    __shared__ __align__(16) uint4 sx[16 * HW];    // 16896 B
    __shared__ float sdisp[4 * HW];                // 1056 B

    const int tid = threadIdx.x;
    // Bijective XCD swizzle: 1024 blocks, 8 XCDs -> 128 consecutive work ids
    // (64 rows x 4 colq of one image) per XCD => halo re-reads are L2-local.
    const int bid = ((int)blockIdx.x & 7) * 128 + ((int)blockIdx.x >> 3);
    const int n       = bid >> 9;
    const int rem     = bid & 511;
    const int rowpair = rem >> 2;                  // 0..127
    const int colq    = rem & 3;
    const int row0    = rowpair << 1;
    const int colbase = colq << 6;                 // 0/64/128/192

    // stage disp halo + x halo strip (fp32 -> bf16 planes), 264 idx < 512
    if (tid < 4 * HW) {
        int rr = tid / HW, cc2 = tid - rr * HW;    // rr 0..3, cc2 0..65
        int gr = row0 + rr - 1, gc = colbase + cc2 - 1;
        bool ok = (gr >= 0) && (gr < IMG) && (gc >= 0) && (gc < IMG);
        float dv = 0.f;
        unsigned w[16];
        #pragma unroll
        for (int j = 0; j < 16; ++j) w[j] = 0u;
        if (ok) {
            dv = disp[(n * IMG + gr) * IMG + gc];
            const float* src = x + ((size_t)(n * IN_C) * IMG + gr) * IMG + gc;
            #pragma unroll
            for (int j = 0; j < 16; ++j) {
                float a = src[(size_t)(2 * j) * (IMG * IMG)];
                float b = src[(size_t)(2 * j + 1) * (IMG * IMG)];
                __hip_bfloat162 h2 = __float22bfloat162_rn(make_float2(a, b));
                w[j] = *reinterpret_cast<unsigned*>(&h2);
            }
        }
        sdisp[tid] = dv;
        sx[(0 * 4 + rr) * HW + cc2] = make_uint4(w[0],  w[1],  w[2],  w[3]);
        sx[(1 * 4 + rr) * HW + cc2] = make_uint4(w[4],  w[5],  w[6],  w[7]);
        sx[(2 * 4 + rr) * HW + cc2] = make_uint4(w[8],  w[9],  w[10], w[11]);
        sx[(3 * 4 + rr) * HW + cc2] = make_uint4(w[12], w[13], w[14], w[15]);
    }
    __syncthreads();   // the only barrier

    const int lane = tid & 63;
    const int wv   = tid >> 6;
    const int ot   = wv & 1;          // out-half: outs [ot*32, ot*32+32)
    const int ph   = (wv >> 1) & 1;   // pixel-half: cols [ph*32, ph*32+32)
    const int rloc = wv >> 2;         // local output row 0/1
    const int l31  = lane & 31;
    const int half = lane >> 5;
    const float fxv = fx[n];
    const float bfx = baseline[n] * fxv;

    // 27 mask bits for this wave's 32 pixels
    const int l = ph * 32 + l31;      // within-block col
    unsigned mbits;
    {
        float dc = sdisp[(rloc + 1) * HW + l + 1];
        float cd = bfx / fminf(fmaxf(dc, 0.01f), 256.f);
        float g  = 16.f * cd / fxv;
        float h  = g * 0.5f;
        unsigned bits = 0u;
        #pragma unroll
        for (int p = 0; p < 9; ++p) {
            int pi = p / 3, pj = p - pi * 3;
            float dval = sdisp[(rloc + pi) * HW + l + pj];
            bool validp = (dval != 0.f) && (dc != 0.f);
            float dmv   = validp ? dval : 0.f;
            float depth = bfx / fminf(fmaxf(dmv, 0.01f), 256.f);
            bool m0 = fabsf(depth - (cd + g)) <= h;
            bool m1 = (fabsf(depth - cd) <= h) || (!validp);
            bool m2 = fabsf(depth - (cd - g)) <= h;
            bits |= ((m0 ? 1u : 0u) << (3 * p))
                  | ((m1 ? 1u : 0u) << (3 * p + 1))
                  | ((m2 ? 1u : 0u) << (3 * p + 2));
        }
        mbits = bits;
    }

    // wave-uniform OR of mask bits -> SGPR (exact skip test)
    unsigned smu;
    {
        unsigned b = mbits;
        #pragma unroll
        for (int off = 32; off >= 1; off >>= 1)
            b |= (unsigned)__shfl_xor((int)b, off, 64);
        smu = __builtin_amdgcn_readfirstlane(b);
    }

    f32x16 acc;
    #pragma unroll
    for (int r = 0; r < 16; ++r) acc[r] = 0.f;

    #pragma unroll
    for (int p = 0; p < 9; ++p) {
        const int pi = p / 3, pj = p - pi * 3;
        if (!((smu >> (3 * p)) & 7u)) continue;    // whole tap dead (scalar)

        // raw bf16 x fragments (lane-contiguous b128 LDS reads)
        B128 xr[2];   // [chalf]; plane s = chalf*2 + half, halo row rloc+pi
        const int cc2 = l + pj;
        #pragma unroll
        for (int ch = 0; ch < 2; ++ch)
            xr[ch].i4 = sx[((ch * 2 + half) * 4 + (rloc + pi)) * HW + cc2];

        #pragma unroll
        for (int t = 0; t < 3; ++t) {
            if ((smu >> (3 * p + t)) & 1u) {       // scalar branch
                unsigned m = 0u - ((mbits >> (3 * p + t)) & 1u);
                B128 a0, a1, b0, b1;
                a0.i4 = wA[(p * 6 + t * 2 + 0) * 128 + ot * 64 + lane];
                a1.i4 = wA[(p * 6 + t * 2 + 1) * 128 + ot * 64 + lane];
                b0.i4 = make_uint4(xr[0].i4.x & m, xr[0].i4.y & m,
                                   xr[0].i4.z & m, xr[0].i4.w & m);
                b1.i4 = make_uint4(xr[1].i4.x & m, xr[1].i4.y & m,
                                   xr[1].i4.z & m, xr[1].i4.w & m);
                acc = __builtin_amdgcn_mfma_f32_32x32x16_bf16(a0.v, b0.v, acc, 0, 0, 0);
                acc = __builtin_amdgcn_mfma_f32_32x32x16_bf16(a1.v, b1.v, acc, 0, 0, 0);
            }
        }
    }

    // epilogue: D[o_local = (reg&3)+8*(reg>>2)+4*half][col = l31] (proven)
    float* ob = out + (size_t)(n * OUT_C) * (IMG * IMG)
              + (size_t)(row0 + rloc) * IMG + colbase + ph * 32 + l31;
    #pragma unroll
    for (int reg = 0; reg < 16; ++reg) {
        int ol = (reg & 3) + 8 * (reg >> 2) + 4 * half + ot * 32;
        ob[(size_t)ol * (IMG * IMG)] = acc[reg];
    }
}

extern "C" void kernel_launch(void* const* d_in, const int* in_sizes, int n_in,
                              void* d_out, int out_size, void* d_ws, size_t ws_size,
                              hipStream_t stream) {
    const float* x        = (const float*)d_in[0];
    const float* disp     = (const float*)d_in[1];
    const float* fx       = (const float*)d_in[2];
    const float* baseline = (const float*)d_in[3];
    const float* w0       = (const float*)d_in[4];
    const float* w1       = (const float*)d_in[5];
    const float* w2       = (const float*)d_in[6];
    float* out            = (float*)d_out;

    __hip_bfloat16* wA = (__hip_bfloat16*)d_ws;   // 54*128*16 = 110592 B

    build_wA<<<54, 128, 0, stream>>>(w0, w1, w2, wA);
    conv25d_mfma7<<<1024, 512, 0, stream>>>(x, disp, fx, baseline,
                                            (const uint4*)wA, out);
}